// Round 23
// baseline (202.432 us; speedup 1.0000x reference)
//
#include <hip/hip_runtime.h>

#define N_NODES 50000
#define N_EDGES 800000
#define NPAD    50008         // slab rows incl. zero pad rows (50000..50007)
#define PADROW  50000         // sentinel src -> zero row
#define NBUCKET 196           // ceil(N_NODES / 256); bucket b = dst in [b*256,(b+1)*256)
#define EPB 4096              // edges per block (16/thread, 196 blocks covers 800K)
#define CPITCH 256            // cnt2d row pitch (ints)
#define BPAD 1792             // max padding per bucket (256 nodes * 7)

typedef __attribute__((ext_vector_type(8))) short bf16x8;
typedef __attribute__((ext_vector_type(4))) float f32x4;

__device__ __forceinline__ int wave_incl_scan(int v, int lane) {
#pragma unroll
    for (int off = 1; off < 64; off <<= 1) {
        int t = __shfl_up(v, off, 64);
        if (lane >= off) v += t;
    }
    return v;
}

// fp32 -> bf16 (round-to-nearest-even), as raw ushort
__device__ __forceinline__ unsigned short f2bf(float f) {
    unsigned int u = __float_as_uint(f);
    u += 0x7FFFu + ((u >> 16) & 1u);
    return (unsigned short)(u >> 16);
}

__device__ __forceinline__ unsigned int pack2bf(float a, float b) {
    return (unsigned int)f2bf(a) | ((unsigned int)f2bf(b) << 16);
}

// ---------- CSR build: 3 dispatches, no global atomics ----------

// Per-block bucket histograms (non-atomic full overwrite -> poison-safe).
// W prep (bf16 transposed weights) rides along as independent work.
__global__ __launch_bounds__(256) void count2d(const int* __restrict__ dst,
                                               int* __restrict__ cnt2d,
                                               const float* __restrict__ W1,
                                               const float* __restrict__ W2,
                                               const float* __restrict__ W3,
                                               unsigned short* __restrict__ wt1,
                                               unsigned short* __restrict__ wt2,
                                               unsigned short* __restrict__ wt3,
                                               int nedges) {
    // ---- W prep ----
    {
        int gid = blockIdx.x * 256 + threadIdx.x;
        if (gid < 16384) {
            wt1[gid] = f2bf(W1[(gid & 127) * 128 + (gid >> 7)]);
        } else if (gid < 32768) {
            int j = gid - 16384;
            wt2[j] = f2bf(W2[(j & 127) * 128 + (j >> 7)]);
        } else if (gid < 40960) {
            int j = gid - 32768;
            wt3[j] = f2bf(W3[(j & 127) * 64 + (j >> 7)]);
        }
    }
    // ---- per-block histogram ----
    __shared__ int h[NBUCKET];
    for (int i = threadIdx.x; i < NBUCKET; i += 256) h[i] = 0;
    __syncthreads();
    const int eb = blockIdx.x * EPB;
#pragma unroll
    for (int i = 0; i < 16; ++i) {
        int e = eb + i * 256 + threadIdx.x;
        if (e < nedges) atomicAdd(&h[dst[e] >> 8], 1);
    }
    __syncthreads();
    for (int i = threadIdx.x; i < NBUCKET; i += 256)
        cnt2d[blockIdx.x * CPITCH + i] = h[i];
}

// Each block derives its own scatter bases from cnt2d (no global cursor
// atomics). Block b publishes bbase[b]; block 0 publishes bbase[NBUCKET].
__global__ __launch_bounds__(256) void partition2(const int* __restrict__ src,
                                                  const int* __restrict__ dst,
                                                  const int* __restrict__ cnt2d,
                                                  int* __restrict__ bbase,
                                                  int* __restrict__ etmp, int nedges) {
    __shared__ int hloc[NBUCKET];   // local per-bucket cursor
    __shared__ int rbase[NBUCKET];  // this block's global base per bucket
    __shared__ int ws4[4];

    const int b   = blockIdx.x;
    const int tid = threadIdx.x;

    for (int i = tid; i < NBUCKET; i += 256) hloc[i] = 0;
    __syncthreads();
    const int eb = b * EPB;
    int d[16], s[16];
#pragma unroll
    for (int i = 0; i < 16; ++i) {
        int e = eb + i * 256 + tid;
        bool ok = e < nedges;
        d[i] = ok ? dst[e] : -1;
        s[i] = ok ? src[e] : 0;
        if (ok) atomicAdd(&hloc[d[i] >> 8], 1);
    }

    int colsum = 0, mypre = 0;
    if (tid < NBUCKET) {
#pragma unroll 4
        for (int blk = 0; blk < NBUCKET; ++blk) {
            int c = cnt2d[blk * CPITCH + tid];
            colsum += c;
            if (blk < b) mypre += c;
        }
    }
    const int lane = tid & 63;
    const int w = tid >> 6;
    int sc = wave_incl_scan(colsum, lane);
    if (lane == 63) ws4[w] = sc;
    __syncthreads();
    int add = 0;
#pragma unroll
    for (int k = 0; k < 4; ++k)
        if (k < w) add += ws4[k];
    const int excl = sc + add - colsum;
    if (tid < NBUCKET) {
        rbase[tid] = excl + mypre;
        if (tid == b) bbase[b] = excl;
    }
    if (b == 0 && tid == 0) bbase[NBUCKET] = nedges;
    __syncthreads();

    for (int i = tid; i < NBUCKET; i += 256) hloc[i] = 0;
    __syncthreads();
#pragma unroll
    for (int i = 0; i < 16; ++i) {
        if (d[i] >= 0) {
            int bk = d[i] >> 8;
            int pos = rbase[bk] + atomicAdd(&hloc[bk], 1);
            etmp[pos] = ((d[i] & 255) << 16) | s[i];
        }
    }
}

// One block per bucket: per-node histogram + PADDED scan -> rowptr (8-aligned
// padded base), pcnt (padded count), norm, node-sorted esrc with PADROW pads.
// Also emits per-bucket degree histogram dh2d[b][64] (bin = pv/8) for degsort.
__global__ __launch_bounds__(256) void build2(const int* __restrict__ etmp,
                                              const int* __restrict__ bbase,
                                              int* __restrict__ rowptr,
                                              unsigned short* __restrict__ pcnt,
                                              unsigned short* __restrict__ esrc,
                                              float* __restrict__ norm,
                                              int* __restrict__ dh2d,
                                              int nnodes, int nedges) {
    const int b = blockIdx.x;
    const int nodebase = b * 256;
    const int nloc = min(256, nnodes - nodebase);
    const int ebeg = bbase[b];
    const int eend = bbase[b + 1];
    const int pbase = ((ebeg + 7) & ~7) + b * BPAD;  // 8-aligned padded base

    __shared__ int h[256];
    __shared__ int cur[256];
    __shared__ int dhist[64];
    h[threadIdx.x] = 0;
    if (threadIdx.x < 64) dhist[threadIdx.x] = 0;
    __syncthreads();

    for (int e = ebeg + threadIdx.x; e < eend; e += 256)
        atomicAdd(&h[etmp[e] >> 16], 1);
    __syncthreads();

    const int lane = threadIdx.x & 63;
    const int w = threadIdx.x >> 6;
    const int v  = h[threadIdx.x];
    const int pv = (v + 7) & ~7;  // padded count
    int sc = wave_incl_scan(pv, lane);
    __shared__ int ws[4];
    if (lane == 63) ws[w] = sc;
    __syncthreads();
    int add = 0;
#pragma unroll
    for (int k = 0; k < 4; ++k)
        if (k < w) add += ws[k];
    const int pexcl = sc + add - pv;
    const int mybeg = pbase + pexcl;

    if (threadIdx.x < nloc) {
        rowptr[nodebase + threadIdx.x] = mybeg;
        pcnt[nodebase + threadIdx.x] = (unsigned short)pv;
        norm[nodebase + threadIdx.x] = v > 0 ? rsqrtf((float)v) : 0.0f;
        int bin = pv >> 3; bin = bin > 63 ? 63 : bin;
        atomicAdd(&dhist[bin], 1);
    }
    cur[threadIdx.x] = pexcl;
    __syncthreads();

    if (threadIdx.x < 64) dh2d[b * 64 + threadIdx.x] = dhist[threadIdx.x];

    // scatter real entries
    for (int e = ebeg + threadIdx.x; e < eend; e += 256) {
        int rec = etmp[e];
        int pos = pbase + atomicAdd(&cur[rec >> 16], 1);
        esrc[pos] = (unsigned short)(rec & 0xFFFF);
    }
    __syncthreads();
    // fill pad slots with PADROW (zero row)
    if (threadIdx.x < nloc) {
        for (int p = mybeg + v; p < mybeg + pv; ++p)
            esrc[p] = (unsigned short)PADROW;
    }
}

// Degree-sorted node permutation: nodes grouped by padded-degree bin so that
// each aggregate wave's 16 node-groups have near-equal iteration counts.
__global__ __launch_bounds__(256) void degscat(const int* __restrict__ dh2d,
                                               const unsigned short* __restrict__ pcnt,
                                               unsigned short* __restrict__ nodeperm,
                                               int nnodes, int nbuckets) {
    __shared__ int rb[64];
    __shared__ int cur[64];
    const int b = blockIdx.x;
    const int tid = threadIdx.x;
    if (tid < 64) {
        int colsum = 0, mypre = 0;
        for (int blk = 0; blk < nbuckets; ++blk) {
            int c = dh2d[blk * 64 + tid];
            colsum += c;
            if (blk < b) mypre += c;
        }
        int sc = wave_incl_scan(colsum, tid);   // inclusive scan in wave 0
        rb[tid] = sc - colsum + mypre;          // exclusive + cross-block prefix
        cur[tid] = 0;
    }
    __syncthreads();
    const int node = b * 256 + tid;
    if (node < nnodes) {
        int bin = pcnt[node] >> 3; bin = bin > 63 ? 63 : bin;
        int pos = rb[bin] + atomicAdd(&cur[bin], 1);
        nodeperm[pos] = (unsigned short)node;
    }
}

// ---------- MFMA GEMM: C_slab = bf16( norm[r] * X @ W ) ----------
// BF16IN=false: X fp32, exactness via hi/lo bf16 split (2 chained MFMAs).
// BF16IN=true : X bf16 row-major (one uint4 load = A fragment, single MFMA).
// LDS holds only Wt (bf16, XOR swizzle (col&7)<<4).
// Output: OUT/32 slabs of [NPAD x 32] bf16; rows >= nnodes written as ZERO
// (nrm=0) so PADROW gathers contribute nothing.
template <int OUT, bool BF16IN>
__global__ __launch_bounds__(256) void gemm_mfma(const void* __restrict__ Xv,
                                                 const unsigned short* __restrict__ Wt,
                                                 const float* __restrict__ norm,
                                                 unsigned short* __restrict__ C, int nrows) {
    constexpr int ROWS = (OUT == 128) ? 32 : 64;
    __shared__ unsigned short Wlds[OUT * 128];   // 32/16 KB

    const int t = threadIdx.x;
    const int rowbase = blockIdx.x * ROWS;
    const int lastrow = nrows - 1;

    {
        const ushort4* __restrict__ Wt4 = reinterpret_cast<const ushort4*>(Wt);
        char* wb = reinterpret_cast<char*>(Wlds);
        for (int i = t; i < OUT * 32; i += 256) {
            ushort4 v = Wt4[i];
            int byte = i << 3;
            int n = byte >> 8;
            *reinterpret_cast<ushort4*>(wb + (byte ^ ((n & 7) << 4))) = v;
        }
    }
    __syncthreads();

    const int w   = t >> 6;
    const int l   = t & 63;
    const int r16 = l & 15;
    const int ks  = l >> 4;

    const int rw = (OUT == 128) ? (w & 1) : w;
    const int ch = (OUT == 128) ? (w >> 1) : 0;

    int grow = rowbase + rw * 16 + r16;
    grow = grow < lastrow ? grow : lastrow;

    const char* wbp = reinterpret_cast<const char*>(Wlds);

    bf16x8 ahi[4], alo[4];
    if constexpr (BF16IN) {
        const uint4* __restrict__ X4 = reinterpret_cast<const uint4*>(Xv);
#pragma unroll
        for (int kk = 0; kk < 4; ++kk) {
            uint4 v = X4[(size_t)grow * 16 + kk * 4 + ks];
            ahi[kk] = *reinterpret_cast<const bf16x8*>(&v);
        }
    } else {
        const float4* __restrict__ X4 = reinterpret_cast<const float4*>(Xv);
#pragma unroll
        for (int kk = 0; kk < 4; ++kk) {
            float4 v0 = X4[(size_t)grow * 32 + kk * 8 + ks * 2];
            float4 v1 = X4[(size_t)grow * 32 + kk * 8 + ks * 2 + 1];
            float xv[8] = {v0.x, v0.y, v0.z, v0.w, v1.x, v1.y, v1.z, v1.w};
#pragma unroll
            for (int j = 0; j < 8; ++j) {
                unsigned short h = f2bf(xv[j]);
                float hf = __uint_as_float(((unsigned int)h) << 16);
                unsigned short lo = f2bf(xv[j] - hf);
                ahi[kk][j] = (short)h;
                alo[kk][j] = (short)lo;
            }
        }
    }

    const int orow0 = rowbase + rw * 16 + ks * 4;
    float nrm[4];
#pragma unroll
    for (int r = 0; r < 4; ++r) {
        int rr = orow0 + r;
        nrm[r] = (rr < nrows) ? norm[rr] : 0.0f;  // pad rows -> zero output
    }

    const size_t slab = (size_t)NPAD * 32;
#pragma unroll
    for (int n = 0; n < 4; ++n) {
        f32x4 acc = {0.f, 0.f, 0.f, 0.f};
        const int col = (ch * 4 + n) * 16 + r16;
#pragma unroll
        for (int kk = 0; kk < 4; ++kk) {
            int byteB = col * 256 + kk * 64 + ks * 16;
            byteB ^= ((col & 7) << 4);
            bf16x8 bfrag = *reinterpret_cast<const bf16x8*>(wbp + byteB);
            if constexpr (!BF16IN)
                acc = __builtin_amdgcn_mfma_f32_16x16x32_bf16(alo[kk], bfrag, acc, 0, 0, 0);
            acc = __builtin_amdgcn_mfma_f32_16x16x32_bf16(ahi[kk], bfrag, acc, 0, 0, 0);
        }
        const int s  = col >> 5;
        const int cs = col & 31;
        unsigned short* cp = C + (size_t)s * slab + (size_t)orow0 * 32 + cs;
#pragma unroll
        for (int r = 0; r < 4; ++r) {
            if (orow0 + r < NPAD)
                cp[(size_t)r * 32] = f2bf(acc[r] * nrm[r]);
        }
    }
}

// ---------- Column-sliced bf16 gather-aggregate (mask-free, degree-sorted) ----------
// feat slice-major bf16 (F/32 slabs of [NPAD x 32], 64 B rows, ~3.2 MB slab).
// slice = blockIdx.x % NSLICE rides block->XCD round-robin: slab L2-resident.
// 4-lane group owns one node taken from the degree-sorted permutation so a
// wave's 16 groups run near-equal iteration counts. Edge lists are 8-aligned +
// PADROW-padded: one aligned uint4 load = 8 indices, 8 UNCONDITIONAL gathers.
template <int F, bool RELU, bool OUTBF16>
__global__ __launch_bounds__(256) void aggregate_bf16(const unsigned short* __restrict__ feat,
                                                      const int* __restrict__ rowptr,
                                                      const unsigned short* __restrict__ pcnt,
                                                      const unsigned short* __restrict__ esrc,
                                                      const unsigned short* __restrict__ nodeperm,
                                                      const float* __restrict__ norm,
                                                      const float* __restrict__ b,
                                                      void* __restrict__ outv,
                                                      int nnodes, int nchunks) {
    constexpr int NSLICE = F / 32;
    const int slice = blockIdx.x % NSLICE;
    const int chunk = blockIdx.x / NSLICE;
    const int span  = (nnodes + nchunks - 1) / nchunks;
    const int nbeg  = chunk * span;
    const int nend  = min(nnodes, nbeg + span);

    const int grp = threadIdx.x >> 2;   // 64 groups per block
    const int l4  = threadIdx.x & 3;    // uint4 (8 bf16 cols) within 32-col slice

    const uint4* __restrict__ slab4 =
        reinterpret_cast<const uint4*>(feat) + (size_t)slice * NPAD * 4;
    const float4* __restrict__ b4 = reinterpret_cast<const float4*>(b);
    const float4 bb0 = b4[slice * 8 + l4 * 2];
    const float4 bb1 = b4[slice * 8 + l4 * 2 + 1];

    for (int pi = nbeg + grp; pi < nend; pi += 64) {
        const int node = (int)nodeperm[pi];
        const int beg = rowptr[node];
        const int cnt = pcnt[node];

        float4 aA[8], aB[8];
#pragma unroll
        for (int i = 0; i < 8; ++i) {
            aA[i] = make_float4(0.f, 0.f, 0.f, 0.f);
            aB[i] = make_float4(0.f, 0.f, 0.f, 0.f);
        }

        for (int e = beg; e < beg + cnt; e += 8) {
            const uint4 iv = *reinterpret_cast<const uint4*>(&esrc[e]);
            int id[8];
            id[0] = (int)(iv.x & 0xFFFFu); id[1] = (int)(iv.x >> 16);
            id[2] = (int)(iv.y & 0xFFFFu); id[3] = (int)(iv.y >> 16);
            id[4] = (int)(iv.z & 0xFFFFu); id[5] = (int)(iv.z >> 16);
            id[6] = (int)(iv.w & 0xFFFFu); id[7] = (int)(iv.w >> 16);
            uint4 v[8];
#pragma unroll
            for (int i = 0; i < 8; ++i) v[i] = slab4[(size_t)id[i] * 4 + l4];
#pragma unroll
            for (int i = 0; i < 8; ++i) {
                aA[i].x += __uint_as_float(v[i].x << 16);
                aA[i].y += __uint_as_float(v[i].x & 0xFFFF0000u);
                aA[i].z += __uint_as_float(v[i].y << 16);
                aA[i].w += __uint_as_float(v[i].y & 0xFFFF0000u);
                aB[i].x += __uint_as_float(v[i].z << 16);
                aB[i].y += __uint_as_float(v[i].z & 0xFFFF0000u);
                aB[i].z += __uint_as_float(v[i].w << 16);
                aB[i].w += __uint_as_float(v[i].w & 0xFFFF0000u);
            }
        }

        float4 a0, a1;
        a0.x = ((aA[0].x + aA[1].x) + (aA[2].x + aA[3].x)) + ((aA[4].x + aA[5].x) + (aA[6].x + aA[7].x));
        a0.y = ((aA[0].y + aA[1].y) + (aA[2].y + aA[3].y)) + ((aA[4].y + aA[5].y) + (aA[6].y + aA[7].y));
        a0.z = ((aA[0].z + aA[1].z) + (aA[2].z + aA[3].z)) + ((aA[4].z + aA[5].z) + (aA[6].z + aA[7].z));
        a0.w = ((aA[0].w + aA[1].w) + (aA[2].w + aA[3].w)) + ((aA[4].w + aA[5].w) + (aA[6].w + aA[7].w));
        a1.x = ((aB[0].x + aB[1].x) + (aB[2].x + aB[3].x)) + ((aB[4].x + aB[5].x) + (aB[6].x + aB[7].x));
        a1.y = ((aB[0].y + aB[1].y) + (aB[2].y + aB[3].y)) + ((aB[4].y + aB[5].y) + (aB[6].y + aB[7].y));
        a1.z = ((aB[0].z + aB[1].z) + (aB[2].z + aB[3].z)) + ((aB[4].z + aB[5].z) + (aB[6].z + aB[7].z));
        a1.w = ((aB[0].w + aB[1].w) + (aB[2].w + aB[3].w)) + ((aB[4].w + aB[5].w) + (aB[6].w + aB[7].w));

        const float nm = norm[node];
        float4 o0, o1;
        o0.x = a0.x * nm + bb0.x; o0.y = a0.y * nm + bb0.y;
        o0.z = a0.z * nm + bb0.z; o0.w = a0.w * nm + bb0.w;
        o1.x = a1.x * nm + bb1.x; o1.y = a1.y * nm + bb1.y;
        o1.z = a1.z * nm + bb1.z; o1.w = a1.w * nm + bb1.w;
        if (RELU) {
            o0.x = fmaxf(o0.x, 0.f); o0.y = fmaxf(o0.y, 0.f);
            o0.z = fmaxf(o0.z, 0.f); o0.w = fmaxf(o0.w, 0.f);
            o1.x = fmaxf(o1.x, 0.f); o1.y = fmaxf(o1.y, 0.f);
            o1.z = fmaxf(o1.z, 0.f); o1.w = fmaxf(o1.w, 0.f);
        }
        if constexpr (OUTBF16) {
            uint4 p;
            p.x = pack2bf(o0.x, o0.y);
            p.y = pack2bf(o0.z, o0.w);
            p.z = pack2bf(o1.x, o1.y);
            p.w = pack2bf(o1.z, o1.w);
            reinterpret_cast<uint4*>(outv)[(size_t)node * (F / 8) + slice * 4 + l4] = p;
        } else {
            float4* op = reinterpret_cast<float4*>(outv) + (size_t)node * (F / 4) + slice * 8 + l4 * 2;
            op[0] = o0;
            op[1] = o1;
        }
    }
}

extern "C" void kernel_launch(void* const* d_in, const int* in_sizes, int n_in,
                              void* d_out, int out_size, void* d_ws, size_t ws_size,
                              hipStream_t stream) {
    const float* features = (const float*)d_in[0];
    const int*   src      = (const int*)d_in[1];
    const int*   dst      = (const int*)d_in[2];
    const float* W1 = (const float*)d_in[3];
    const float* b1 = (const float*)d_in[4];
    const float* W2 = (const float*)d_in[5];
    const float* b2 = (const float*)d_in[6];
    const float* W3 = (const float*)d_in[7];
    const float* b3 = (const float*)d_in[8];
    float* out = (float*)d_out;

    auto align256 = [](size_t x) { return (x + 255) / 256 * 256; };
    char* ws = (char*)d_ws;
    size_t off = 0;
    int*   cnt2d   = (int*)(ws + off);   off += align256((size_t)NBUCKET * CPITCH * 4);
    int*   dh2d    = (int*)(ws + off);   off += align256((size_t)NBUCKET * 64 * 4);
    int*   bbase   = (int*)(ws + off);   off += align256(((size_t)NBUCKET + 1) * 4);
    float* norm    = (float*)(ws + off); off += align256((size_t)N_NODES * 4);
    int*   rowptr  = (int*)(ws + off);   off += align256((size_t)N_NODES * 4);
    unsigned short* pcnt = (unsigned short*)(ws + off); off += align256((size_t)N_NODES * 2);
    unsigned short* nodeperm = (unsigned short*)(ws + off); off += align256((size_t)N_NODES * 2);
    int*   etmp    = (int*)(ws + off);   off += align256((size_t)N_EDGES * 4);
    unsigned short* esrc = (unsigned short*)(ws + off);
    off += align256(((size_t)N_EDGES + 8 + (size_t)NBUCKET * BPAD) * 2);
    unsigned short* wt1 = (unsigned short*)(ws + off); off += align256((size_t)128 * 128 * 2);
    unsigned short* wt2 = (unsigned short*)(ws + off); off += align256((size_t)128 * 128 * 2);
    unsigned short* wt3 = (unsigned short*)(ws + off); off += align256((size_t)64 * 128 * 2);
    unsigned short* slab = (unsigned short*)(ws + off); off += align256((size_t)NPAD * 128 * 2);
    unsigned short* hbf  = (unsigned short*)(ws + off); off += align256((size_t)N_NODES * 128 * 2);

    const int gemm128_blks = (N_NODES + 31) / 32;  // 1563 (covers NPAD rows)
    const int gemm64_blks  = (N_NODES + 63) / 64;  // 782
    const int chunks = (N_NODES + 63) / 64;        // span 64 -> 1 node per 4-lane group

    // ---- CSR build (no memset, no global atomics) + degree-sorted perm ----
    count2d<<<NBUCKET, 256, 0, stream>>>(dst, cnt2d, W1, W2, W3, wt1, wt2, wt3, N_EDGES);
    partition2<<<NBUCKET, 256, 0, stream>>>(src, dst, cnt2d, bbase, etmp, N_EDGES);
    build2<<<NBUCKET, 256, 0, stream>>>(etmp, bbase, rowptr, pcnt, esrc, norm, dh2d,
                                        N_NODES, N_EDGES);
    degscat<<<NBUCKET, 256, 0, stream>>>(dh2d, pcnt, nodeperm, N_NODES, NBUCKET);

    // ---- Layer 1: features (fp32, exact hi/lo) -> slab -> hbf (h1, bf16) ----
    gemm_mfma<128, false><<<gemm128_blks, 256, 0, stream>>>(features, wt1, norm, slab, N_NODES);
    aggregate_bf16<128, true, true><<<chunks * 4, 256, 0, stream>>>(slab, rowptr, pcnt, esrc, nodeperm, norm, b1, hbf, N_NODES, chunks);

    // ---- Layer 2: hbf (bf16) -> slab -> hbf (h2, bf16) ----
    gemm_mfma<128, true><<<gemm128_blks, 256, 0, stream>>>(hbf, wt2, norm, slab, N_NODES);
    aggregate_bf16<128, true, true><<<chunks * 4, 256, 0, stream>>>(slab, rowptr, pcnt, esrc, nodeperm, norm, b2, hbf, N_NODES, chunks);

    // ---- Layer 3: hbf (bf16) -> slab (64 cols) -> d_out (fp32) ----
    gemm_mfma<64, true><<<gemm64_blks, 256, 0, stream>>>(hbf, wt3, norm, slab, N_NODES);
    aggregate_bf16<64, false, false><<<chunks * 2, 256, 0, stream>>>(slab, rowptr, pcnt, esrc, nodeperm, norm, b3, out, N_NODES, chunks);
}

// Round 24
// 168.391 us; speedup vs baseline: 1.2022x; 1.2022x over previous
//
#include <hip/hip_runtime.h>

#define N_NODES 50000
#define N_EDGES 800000
#define NPAD    50008         // slab rows incl. zero pad rows (50000..50007)
#define PADROW  50000         // sentinel src -> zero row
#define NBUCKET 196           // ceil(N_NODES / 256); bucket b = dst in [b*256,(b+1)*256)
#define EPB 4096              // edges per block (16/thread, 196 blocks covers 800K)
#define CPITCH 256            // cnt2d row pitch (ints)
#define BPAD 1792             // max padding per bucket (256 nodes * 7)

typedef __attribute__((ext_vector_type(8))) short bf16x8;
typedef __attribute__((ext_vector_type(4))) float f32x4;

__device__ __forceinline__ int wave_incl_scan(int v, int lane) {
#pragma unroll
    for (int off = 1; off < 64; off <<= 1) {
        int t = __shfl_up(v, off, 64);
        if (lane >= off) v += t;
    }
    return v;
}

// fp32 -> bf16 (round-to-nearest-even), as raw ushort
__device__ __forceinline__ unsigned short f2bf(float f) {
    unsigned int u = __float_as_uint(f);
    u += 0x7FFFu + ((u >> 16) & 1u);
    return (unsigned short)(u >> 16);
}

__device__ __forceinline__ unsigned int pack2bf(float a, float b) {
    return (unsigned int)f2bf(a) | ((unsigned int)f2bf(b) << 16);
}

// ---------- CSR build: 3 dispatches, no global atomics ----------

// Per-block bucket histograms (non-atomic full overwrite -> poison-safe).
// W prep (bf16 transposed weights) rides along as independent work.
__global__ __launch_bounds__(256) void count2d(const int* __restrict__ dst,
                                               int* __restrict__ cnt2d,
                                               const float* __restrict__ W1,
                                               const float* __restrict__ W2,
                                               const float* __restrict__ W3,
                                               unsigned short* __restrict__ wt1,
                                               unsigned short* __restrict__ wt2,
                                               unsigned short* __restrict__ wt3,
                                               int nedges) {
    // ---- W prep ----
    {
        int gid = blockIdx.x * 256 + threadIdx.x;
        if (gid < 16384) {
            wt1[gid] = f2bf(W1[(gid & 127) * 128 + (gid >> 7)]);
        } else if (gid < 32768) {
            int j = gid - 16384;
            wt2[j] = f2bf(W2[(j & 127) * 128 + (j >> 7)]);
        } else if (gid < 40960) {
            int j = gid - 32768;
            wt3[j] = f2bf(W3[(j & 127) * 64 + (j >> 7)]);
        }
    }
    // ---- per-block histogram ----
    __shared__ int h[NBUCKET];
    for (int i = threadIdx.x; i < NBUCKET; i += 256) h[i] = 0;
    __syncthreads();
    const int eb = blockIdx.x * EPB;
#pragma unroll
    for (int i = 0; i < 16; ++i) {
        int e = eb + i * 256 + threadIdx.x;
        if (e < nedges) atomicAdd(&h[dst[e] >> 8], 1);
    }
    __syncthreads();
    for (int i = threadIdx.x; i < NBUCKET; i += 256)
        cnt2d[blockIdx.x * CPITCH + i] = h[i];
}

// Each block derives its own scatter bases from cnt2d (no global cursor
// atomics). Block b publishes bbase[b]; block 0 publishes bbase[NBUCKET].
__global__ __launch_bounds__(256) void partition2(const int* __restrict__ src,
                                                  const int* __restrict__ dst,
                                                  const int* __restrict__ cnt2d,
                                                  int* __restrict__ bbase,
                                                  int* __restrict__ etmp, int nedges) {
    __shared__ int hloc[NBUCKET];   // local per-bucket cursor
    __shared__ int rbase[NBUCKET];  // this block's global base per bucket
    __shared__ int ws4[4];

    const int b   = blockIdx.x;
    const int tid = threadIdx.x;

    for (int i = tid; i < NBUCKET; i += 256) hloc[i] = 0;
    __syncthreads();
    const int eb = b * EPB;
    int d[16], s[16];
#pragma unroll
    for (int i = 0; i < 16; ++i) {
        int e = eb + i * 256 + tid;
        bool ok = e < nedges;
        d[i] = ok ? dst[e] : -1;
        s[i] = ok ? src[e] : 0;
        if (ok) atomicAdd(&hloc[d[i] >> 8], 1);
    }

    int colsum = 0, mypre = 0;
    if (tid < NBUCKET) {
#pragma unroll 4
        for (int blk = 0; blk < NBUCKET; ++blk) {
            int c = cnt2d[blk * CPITCH + tid];
            colsum += c;
            if (blk < b) mypre += c;
        }
    }
    const int lane = tid & 63;
    const int w = tid >> 6;
    int sc = wave_incl_scan(colsum, lane);
    if (lane == 63) ws4[w] = sc;
    __syncthreads();
    int add = 0;
#pragma unroll
    for (int k = 0; k < 4; ++k)
        if (k < w) add += ws4[k];
    const int excl = sc + add - colsum;
    if (tid < NBUCKET) {
        rbase[tid] = excl + mypre;
        if (tid == b) bbase[b] = excl;
    }
    if (b == 0 && tid == 0) bbase[NBUCKET] = nedges;
    __syncthreads();

    for (int i = tid; i < NBUCKET; i += 256) hloc[i] = 0;
    __syncthreads();
#pragma unroll
    for (int i = 0; i < 16; ++i) {
        if (d[i] >= 0) {
            int bk = d[i] >> 8;
            int pos = rbase[bk] + atomicAdd(&hloc[bk], 1);
            etmp[pos] = ((d[i] & 255) << 16) | s[i];
        }
    }
}

// One block per bucket: per-node histogram + PADDED scan -> rowptr (8-aligned
// padded base), pcnt (padded count), norm, node-sorted esrc with PADROW pads.
__global__ __launch_bounds__(256) void build2(const int* __restrict__ etmp,
                                              const int* __restrict__ bbase,
                                              int* __restrict__ rowptr,
                                              unsigned short* __restrict__ pcnt,
                                              unsigned short* __restrict__ esrc,
                                              float* __restrict__ norm,
                                              int nnodes, int nedges) {
    const int b = blockIdx.x;
    const int nodebase = b * 256;
    const int nloc = min(256, nnodes - nodebase);
    const int ebeg = bbase[b];
    const int eend = bbase[b + 1];
    const int pbase = ((ebeg + 7) & ~7) + b * BPAD;  // 8-aligned padded base

    __shared__ int h[256];
    __shared__ int cur[256];
    h[threadIdx.x] = 0;
    __syncthreads();

    for (int e = ebeg + threadIdx.x; e < eend; e += 256)
        atomicAdd(&h[etmp[e] >> 16], 1);
    __syncthreads();

    const int lane = threadIdx.x & 63;
    const int w = threadIdx.x >> 6;
    const int v  = h[threadIdx.x];
    const int pv = (v + 7) & ~7;  // padded count
    int sc = wave_incl_scan(pv, lane);
    __shared__ int ws[4];
    if (lane == 63) ws[w] = sc;
    __syncthreads();
    int add = 0;
#pragma unroll
    for (int k = 0; k < 4; ++k)
        if (k < w) add += ws[k];
    const int pexcl = sc + add - pv;
    const int mybeg = pbase + pexcl;

    if (threadIdx.x < nloc) {
        rowptr[nodebase + threadIdx.x] = mybeg;
        pcnt[nodebase + threadIdx.x] = (unsigned short)pv;
        norm[nodebase + threadIdx.x] = v > 0 ? rsqrtf((float)v) : 0.0f;
    }
    cur[threadIdx.x] = pexcl;
    __syncthreads();

    // scatter real entries
    for (int e = ebeg + threadIdx.x; e < eend; e += 256) {
        int rec = etmp[e];
        int pos = pbase + atomicAdd(&cur[rec >> 16], 1);
        esrc[pos] = (unsigned short)(rec & 0xFFFF);
    }
    __syncthreads();
    // fill pad slots with PADROW (zero row)
    if (threadIdx.x < nloc) {
        for (int p = mybeg + v; p < mybeg + pv; ++p)
            esrc[p] = (unsigned short)PADROW;
    }
}

// ---------- MFMA GEMM: C_slab = bf16( norm[r] * X @ W ) ----------
// BF16IN=false: X fp32, exactness via hi/lo bf16 split (2 chained MFMAs).
// BF16IN=true : X bf16 row-major (one uint4 load = A fragment, single MFMA).
// LDS holds only Wt (bf16, XOR swizzle (col&7)<<4).
// Output: OUT/32 slabs of [NPAD x 32] bf16; rows >= nnodes written as ZERO
// (nrm=0) so PADROW gathers contribute nothing.
template <int OUT, bool BF16IN>
__global__ __launch_bounds__(256) void gemm_mfma(const void* __restrict__ Xv,
                                                 const unsigned short* __restrict__ Wt,
                                                 const float* __restrict__ norm,
                                                 unsigned short* __restrict__ C, int nrows) {
    constexpr int ROWS = (OUT == 128) ? 32 : 64;
    __shared__ unsigned short Wlds[OUT * 128];   // 32/16 KB

    const int t = threadIdx.x;
    const int rowbase = blockIdx.x * ROWS;
    const int lastrow = nrows - 1;

    {
        const ushort4* __restrict__ Wt4 = reinterpret_cast<const ushort4*>(Wt);
        char* wb = reinterpret_cast<char*>(Wlds);
        for (int i = t; i < OUT * 32; i += 256) {
            ushort4 v = Wt4[i];
            int byte = i << 3;
            int n = byte >> 8;
            *reinterpret_cast<ushort4*>(wb + (byte ^ ((n & 7) << 4))) = v;
        }
    }
    __syncthreads();

    const int w   = t >> 6;
    const int l   = t & 63;
    const int r16 = l & 15;
    const int ks  = l >> 4;

    const int rw = (OUT == 128) ? (w & 1) : w;
    const int ch = (OUT == 128) ? (w >> 1) : 0;

    int grow = rowbase + rw * 16 + r16;
    grow = grow < lastrow ? grow : lastrow;

    const char* wbp = reinterpret_cast<const char*>(Wlds);

    bf16x8 ahi[4], alo[4];
    if constexpr (BF16IN) {
        const uint4* __restrict__ X4 = reinterpret_cast<const uint4*>(Xv);
#pragma unroll
        for (int kk = 0; kk < 4; ++kk) {
            uint4 v = X4[(size_t)grow * 16 + kk * 4 + ks];
            ahi[kk] = *reinterpret_cast<const bf16x8*>(&v);
        }
    } else {
        const float4* __restrict__ X4 = reinterpret_cast<const float4*>(Xv);
#pragma unroll
        for (int kk = 0; kk < 4; ++kk) {
            float4 v0 = X4[(size_t)grow * 32 + kk * 8 + ks * 2];
            float4 v1 = X4[(size_t)grow * 32 + kk * 8 + ks * 2 + 1];
            float xv[8] = {v0.x, v0.y, v0.z, v0.w, v1.x, v1.y, v1.z, v1.w};
#pragma unroll
            for (int j = 0; j < 8; ++j) {
                unsigned short h = f2bf(xv[j]);
                float hf = __uint_as_float(((unsigned int)h) << 16);
                unsigned short lo = f2bf(xv[j] - hf);
                ahi[kk][j] = (short)h;
                alo[kk][j] = (short)lo;
            }
        }
    }

    const int orow0 = rowbase + rw * 16 + ks * 4;
    float nrm[4];
#pragma unroll
    for (int r = 0; r < 4; ++r) {
        int rr = orow0 + r;
        nrm[r] = (rr < nrows) ? norm[rr] : 0.0f;  // pad rows -> zero output
    }

    const size_t slab = (size_t)NPAD * 32;
#pragma unroll
    for (int n = 0; n < 4; ++n) {
        f32x4 acc = {0.f, 0.f, 0.f, 0.f};
        const int col = (ch * 4 + n) * 16 + r16;
#pragma unroll
        for (int kk = 0; kk < 4; ++kk) {
            int byteB = col * 256 + kk * 64 + ks * 16;
            byteB ^= ((col & 7) << 4);
            bf16x8 bfrag = *reinterpret_cast<const bf16x8*>(wbp + byteB);
            if constexpr (!BF16IN)
                acc = __builtin_amdgcn_mfma_f32_16x16x32_bf16(alo[kk], bfrag, acc, 0, 0, 0);
            acc = __builtin_amdgcn_mfma_f32_16x16x32_bf16(ahi[kk], bfrag, acc, 0, 0, 0);
        }
        const int s  = col >> 5;
        const int cs = col & 31;
        unsigned short* cp = C + (size_t)s * slab + (size_t)orow0 * 32 + cs;
#pragma unroll
        for (int r = 0; r < 4; ++r) {
            if (orow0 + r < NPAD)
                cp[(size_t)r * 32] = f2bf(acc[r] * nrm[r]);
        }
    }
}

// ---------- Column-sliced bf16 gather-aggregate (mask-free, padded lists) ----------
// feat slice-major bf16 (F/32 slabs of [NPAD x 32], 64 B rows, ~3.2 MB slab).
// slice = blockIdx.x % NSLICE rides block->XCD round-robin: slab L2-resident.
// 4-lane group owns one node (natural order preserves rowptr/esrc/output
// locality). Edge lists are 8-aligned + PADROW-padded: one aligned uint4 load
// = 8 indices, then 8 UNCONDITIONAL gathers + adds.
template <int F, bool RELU, bool OUTBF16>
__global__ __launch_bounds__(256) void aggregate_bf16(const unsigned short* __restrict__ feat,
                                                      const int* __restrict__ rowptr,
                                                      const unsigned short* __restrict__ pcnt,
                                                      const unsigned short* __restrict__ esrc,
                                                      const float* __restrict__ norm,
                                                      const float* __restrict__ b,
                                                      void* __restrict__ outv,
                                                      int nnodes, int nchunks) {
    constexpr int NSLICE = F / 32;
    const int slice = blockIdx.x % NSLICE;
    const int chunk = blockIdx.x / NSLICE;
    const int span  = (nnodes + nchunks - 1) / nchunks;
    const int nbeg  = chunk * span;
    const int nend  = min(nnodes, nbeg + span);

    const int grp = threadIdx.x >> 2;   // 64 groups per block
    const int l4  = threadIdx.x & 3;    // uint4 (8 bf16 cols) within 32-col slice

    const uint4* __restrict__ slab4 =
        reinterpret_cast<const uint4*>(feat) + (size_t)slice * NPAD * 4;
    const float4* __restrict__ b4 = reinterpret_cast<const float4*>(b);
    const float4 bb0 = b4[slice * 8 + l4 * 2];
    const float4 bb1 = b4[slice * 8 + l4 * 2 + 1];

    for (int node = nbeg + grp; node < nend; node += 64) {
        const int beg = rowptr[node];
        const int cnt = pcnt[node];

        float4 aA[8], aB[8];
#pragma unroll
        for (int i = 0; i < 8; ++i) {
            aA[i] = make_float4(0.f, 0.f, 0.f, 0.f);
            aB[i] = make_float4(0.f, 0.f, 0.f, 0.f);
        }

        for (int e = beg; e < beg + cnt; e += 8) {
            const uint4 iv = *reinterpret_cast<const uint4*>(&esrc[e]);
            int id[8];
            id[0] = (int)(iv.x & 0xFFFFu); id[1] = (int)(iv.x >> 16);
            id[2] = (int)(iv.y & 0xFFFFu); id[3] = (int)(iv.y >> 16);
            id[4] = (int)(iv.z & 0xFFFFu); id[5] = (int)(iv.z >> 16);
            id[6] = (int)(iv.w & 0xFFFFu); id[7] = (int)(iv.w >> 16);
            uint4 v[8];
#pragma unroll
            for (int i = 0; i < 8; ++i) v[i] = slab4[(size_t)id[i] * 4 + l4];
#pragma unroll
            for (int i = 0; i < 8; ++i) {
                aA[i].x += __uint_as_float(v[i].x << 16);
                aA[i].y += __uint_as_float(v[i].x & 0xFFFF0000u);
                aA[i].z += __uint_as_float(v[i].y << 16);
                aA[i].w += __uint_as_float(v[i].y & 0xFFFF0000u);
                aB[i].x += __uint_as_float(v[i].z << 16);
                aB[i].y += __uint_as_float(v[i].z & 0xFFFF0000u);
                aB[i].z += __uint_as_float(v[i].w << 16);
                aB[i].w += __uint_as_float(v[i].w & 0xFFFF0000u);
            }
        }

        float4 a0, a1;
        a0.x = ((aA[0].x + aA[1].x) + (aA[2].x + aA[3].x)) + ((aA[4].x + aA[5].x) + (aA[6].x + aA[7].x));
        a0.y = ((aA[0].y + aA[1].y) + (aA[2].y + aA[3].y)) + ((aA[4].y + aA[5].y) + (aA[6].y + aA[7].y));
        a0.z = ((aA[0].z + aA[1].z) + (aA[2].z + aA[3].z)) + ((aA[4].z + aA[5].z) + (aA[6].z + aA[7].z));
        a0.w = ((aA[0].w + aA[1].w) + (aA[2].w + aA[3].w)) + ((aA[4].w + aA[5].w) + (aA[6].w + aA[7].w));
        a1.x = ((aB[0].x + aB[1].x) + (aB[2].x + aB[3].x)) + ((aB[4].x + aB[5].x) + (aB[6].x + aB[7].x));
        a1.y = ((aB[0].y + aB[1].y) + (aB[2].y + aB[3].y)) + ((aB[4].y + aB[5].y) + (aB[6].y + aB[7].y));
        a1.z = ((aB[0].z + aB[1].z) + (aB[2].z + aB[3].z)) + ((aB[4].z + aB[5].z) + (aB[6].z + aB[7].z));
        a1.w = ((aB[0].w + aB[1].w) + (aB[2].w + aB[3].w)) + ((aB[4].w + aB[5].w) + (aB[6].w + aB[7].w));

        const float nm = norm[node];
        float4 o0, o1;
        o0.x = a0.x * nm + bb0.x; o0.y = a0.y * nm + bb0.y;
        o0.z = a0.z * nm + bb0.z; o0.w = a0.w * nm + bb0.w;
        o1.x = a1.x * nm + bb1.x; o1.y = a1.y * nm + bb1.y;
        o1.z = a1.z * nm + bb1.z; o1.w = a1.w * nm + bb1.w;
        if (RELU) {
            o0.x = fmaxf(o0.x, 0.f); o0.y = fmaxf(o0.y, 0.f);
            o0.z = fmaxf(o0.z, 0.f); o0.w = fmaxf(o0.w, 0.f);
            o1.x = fmaxf(o1.x, 0.f); o1.y = fmaxf(o1.y, 0.f);
            o1.z = fmaxf(o1.z, 0.f); o1.w = fmaxf(o1.w, 0.f);
        }
        if constexpr (OUTBF16) {
            uint4 p;
            p.x = pack2bf(o0.x, o0.y);
            p.y = pack2bf(o0.z, o0.w);
            p.z = pack2bf(o1.x, o1.y);
            p.w = pack2bf(o1.z, o1.w);
            reinterpret_cast<uint4*>(outv)[(size_t)node * (F / 8) + slice * 4 + l4] = p;
        } else {
            float4* op = reinterpret_cast<float4*>(outv) + (size_t)node * (F / 4) + slice * 8 + l4 * 2;
            op[0] = o0;
            op[1] = o1;
        }
    }
}

extern "C" void kernel_launch(void* const* d_in, const int* in_sizes, int n_in,
                              void* d_out, int out_size, void* d_ws, size_t ws_size,
                              hipStream_t stream) {
    const float* features = (const float*)d_in[0];
    const int*   src      = (const int*)d_in[1];
    const int*   dst      = (const int*)d_in[2];
    const float* W1 = (const float*)d_in[3];
    const float* b1 = (const float*)d_in[4];
    const float* W2 = (const float*)d_in[5];
    const float* b2 = (const float*)d_in[6];
    const float* W3 = (const float*)d_in[7];
    const float* b3 = (const float*)d_in[8];
    float* out = (float*)d_out;

    auto align256 = [](size_t x) { return (x + 255) / 256 * 256; };
    char* ws = (char*)d_ws;
    size_t off = 0;
    int*   cnt2d   = (int*)(ws + off);   off += align256((size_t)NBUCKET * CPITCH * 4);
    int*   bbase   = (int*)(ws + off);   off += align256(((size_t)NBUCKET + 1) * 4);
    float* norm    = (float*)(ws + off); off += align256((size_t)N_NODES * 4);
    int*   rowptr  = (int*)(ws + off);   off += align256((size_t)N_NODES * 4);
    unsigned short* pcnt = (unsigned short*)(ws + off); off += align256((size_t)N_NODES * 2);
    int*   etmp    = (int*)(ws + off);   off += align256((size_t)N_EDGES * 4);
    unsigned short* esrc = (unsigned short*)(ws + off);
    off += align256(((size_t)N_EDGES + 8 + (size_t)NBUCKET * BPAD) * 2);
    unsigned short* wt1 = (unsigned short*)(ws + off); off += align256((size_t)128 * 128 * 2);
    unsigned short* wt2 = (unsigned short*)(ws + off); off += align256((size_t)128 * 128 * 2);
    unsigned short* wt3 = (unsigned short*)(ws + off); off += align256((size_t)64 * 128 * 2);
    unsigned short* slab = (unsigned short*)(ws + off); off += align256((size_t)NPAD * 128 * 2);
    unsigned short* hbf  = (unsigned short*)(ws + off); off += align256((size_t)N_NODES * 128 * 2);

    const int gemm128_blks = (N_NODES + 31) / 32;  // 1563 (covers NPAD rows)
    const int gemm64_blks  = (N_NODES + 63) / 64;  // 782
    const int chunks = (N_NODES + 63) / 64;        // span 64 -> 1 node per 4-lane group

    // ---- CSR build (3 dispatches, no memset, no global atomics) ----
    count2d<<<NBUCKET, 256, 0, stream>>>(dst, cnt2d, W1, W2, W3, wt1, wt2, wt3, N_EDGES);
    partition2<<<NBUCKET, 256, 0, stream>>>(src, dst, cnt2d, bbase, etmp, N_EDGES);
    build2<<<NBUCKET, 256, 0, stream>>>(etmp, bbase, rowptr, pcnt, esrc, norm, N_NODES, N_EDGES);

    // ---- Layer 1: features (fp32, exact hi/lo) -> slab -> hbf (h1, bf16) ----
    gemm_mfma<128, false><<<gemm128_blks, 256, 0, stream>>>(features, wt1, norm, slab, N_NODES);
    aggregate_bf16<128, true, true><<<chunks * 4, 256, 0, stream>>>(slab, rowptr, pcnt, esrc, norm, b1, hbf, N_NODES, chunks);

    // ---- Layer 2: hbf (bf16) -> slab -> hbf (h2, bf16) ----
    gemm_mfma<128, true><<<gemm128_blks, 256, 0, stream>>>(hbf, wt2, norm, slab, N_NODES);
    aggregate_bf16<128, true, true><<<chunks * 4, 256, 0, stream>>>(slab, rowptr, pcnt, esrc, norm, b2, hbf, N_NODES, chunks);

    // ---- Layer 3: hbf (bf16) -> slab (64 cols) -> d_out (fp32) ----
    gemm_mfma<64, true><<<gemm64_blks, 256, 0, stream>>>(hbf, wt3, norm, slab, N_NODES);
    aggregate_bf16<64, false, false><<<chunks * 2, 256, 0, stream>>>(slab, rowptr, pcnt, esrc, norm, b3, out, N_NODES, chunks);
}